// Round 13
// baseline (101.845 us; speedup 1.0000x reference)
//
#include <hip/hip_runtime.h>
#include <math.h>

#define NB 4096
#define ND 1024
#define SCALEF 20.0f
#define SQ 448.0f  // int8 quant scale for unit-norm rows (|x|max ~0.15 -> |q| <= ~67)

typedef int intx4 __attribute__((ext_vector_type(4)));

__device__ __forceinline__ void load16_to_lds(const void* g, void* l) {
    __builtin_amdgcn_global_load_lds(
        (const __attribute__((address_space(1))) void*)g,
        (__attribute__((address_space(3))) void*)l, 16, 0, 0);
}

__device__ __forceinline__ int q8(float x) {
    float c = fminf(fmaxf(x, -127.0f), 127.0f);
    return (int)rintf(c);
}

// ---------------------------------------------------------------------------
// Kernel 1: fused L2-normalize + fp32 -> int8 quantize (q = rint(448 * x^)),
// one wave per row. Packs 4 i8 per dword in k-order. Zeroes rowsum, cnt, out.
// ---------------------------------------------------------------------------
__global__ __launch_bounds__(256) void mnrl_norm_cvt(
    const float* __restrict__ A, const float* __restrict__ P,
    signed char* __restrict__ Aq, signed char* __restrict__ Pq,
    float* __restrict__ rowsum, int* __restrict__ cnt,
    float* __restrict__ out) {
    if (blockIdx.x == 0) {
        if (threadIdx.x == 0) out[0] = 0.0f;
        if (threadIdx.x < 16) cnt[threadIdx.x] = 0;
    }
    int row = blockIdx.x * 4 + (threadIdx.x >> 6);  // 0..8191
    int lane = threadIdx.x & 63;
    bool is_a = row < NB;
    const float* src = is_a ? (A + (size_t)row * ND)
                            : (P + (size_t)(row - NB) * ND);
    unsigned int* dst = (unsigned int*)(is_a ? (Aq + (size_t)row * ND)
                                             : (Pq + (size_t)(row - NB) * ND));

    float4 v[4];
    float ss = 0.0f;
#pragma unroll
    for (int i = 0; i < 4; ++i) {
        v[i] = ((const float4*)src)[i * 64 + lane];
        ss += v[i].x * v[i].x + v[i].y * v[i].y + v[i].z * v[i].z + v[i].w * v[i].w;
    }
#pragma unroll
    for (int off = 32; off > 0; off >>= 1) ss += __shfl_xor(ss, off, 64);
    float inv = SQ / fmaxf(sqrtf(ss), 1e-8f);
#pragma unroll
    for (int i = 0; i < 4; ++i) {
        int q0 = q8(v[i].x * inv), q1 = q8(v[i].y * inv);
        int q2 = q8(v[i].z * inv), q3 = q8(v[i].w * inv);
        dst[i * 64 + lane] = (unsigned int)((q0 & 255) | ((q1 & 255) << 8) |
                                            ((q2 & 255) << 16) | (q3 << 24));
    }
    if (is_a && lane == 0) rowsum[row] = 0.0f;
}

// ---------------------------------------------------------------------------
// Kernel 2: the verified round-6 GEMM body, untouched: 256x256-tile int8
// MFMA (mfma_i32_16x16x64_i8), 8 waves (2Mx4N), BK=64 -> 16 K-steps,
// ring-4 LDS, lookahead-3 prefetch, counted vmcnt(8), 0 bank conflicts.
// Fused exp-sum + diag, plus completion-counter loss finalize using ONLY
// relaxed device-scope atomics (no fences -> no buffer_wbl2/inv storm;
// ordering via __syncthreads' pre-barrier vmcnt(0) drain).
//
// LDS row: 4 chunks of 16 B; chunk c of row r at slot c^((r>>1)&3) (fetch
// side pre-swizzles the per-lane global address; gload_lds dest is linear).
// ---------------------------------------------------------------------------
__global__ __launch_bounds__(512, 2) void mnrl_gemm_lse(
    const signed char* __restrict__ Aq, const signed char* __restrict__ Pq,
    float* __restrict__ rowsum, float* __restrict__ diag,
    int* __restrict__ cnt, float* __restrict__ out) {
    __shared__ __align__(16) unsigned char lds_a[4][256 * 64];
    __shared__ __align__(16) unsigned char lds_b[4][256 * 64];
    __shared__ int is_last;

    // XCD-aware swizzle (256 blocks, 8 XCDs).
    int bid = blockIdx.x;
    int swz = (bid & 7) * 32 + (bid >> 3);
    int tile_m = swz >> 4;
    int tile_n = swz & 15;

    int t = threadIdx.x;
    int lane = t & 63;
    int w = t >> 6;   // 0..7
    int wm = w >> 2;  // 0..1  (128-row half)
    int wn = w & 3;   // 0..3  (64-col quarter)
    int quad = lane >> 4;
    int l16 = lane & 15;

    const signed char* Abase = Aq + (size_t)tile_m * 256 * ND;
    const signed char* Pbase = Pq + (size_t)tile_n * 256 * ND;

    // Staging: lane l -> row (l>>2), LDS slot (l&3); fetch global chunk
    // (l&3)^((l>>3)&3) so slot s of row r holds chunk s^((r>>1)&3).
    int srow = lane >> 2;
    int chunk = (lane & 3) ^ ((lane >> 3) & 3);
    const signed char* srcA0 = Abase + (size_t)(w * 32 + srow) * ND + chunk * 16;
    const signed char* srcA1 = srcA0 + (size_t)16 * ND;
    const signed char* srcP0 = Pbase + (size_t)(w * 32 + srow) * ND + chunk * 16;
    const signed char* srcP1 = srcP0 + (size_t)16 * ND;
    const int dst0 = w * 2048;
    const int dst1 = w * 2048 + 1024;

    // Fragment read byte offsets. Row r: base r*64; slot = quad^((l16>>1)&3).
    int key = (l16 >> 1) & 3;
    int slot16 = (quad ^ key) * 16;
    int offA[8], offB[4];
#pragma unroll
    for (int mt = 0; mt < 8; ++mt)
        offA[mt] = (wm * 128 + mt * 16 + l16) * 64 + slot16;
#pragma unroll
    for (int nt = 0; nt < 4; ++nt)
        offB[nt] = (wn * 64 + nt * 16 + l16) * 64 + slot16;

    intx4 acc[8][4];  // i32 accum (AGPR)
#pragma unroll
    for (int mt = 0; mt < 8; ++mt)
#pragma unroll
        for (int nt = 0; nt < 4; ++nt) acc[mt][nt] = (intx4){0, 0, 0, 0};

#define STAGE(KT)                                                   \
    {                                                               \
        int koff_ = (KT) * 64;                                      \
        int b_ = (KT) & 3;                                          \
        load16_to_lds(srcA0 + koff_, &lds_a[b_][dst0]);             \
        load16_to_lds(srcA1 + koff_, &lds_a[b_][dst1]);             \
        load16_to_lds(srcP0 + koff_, &lds_b[b_][dst0]);             \
        load16_to_lds(srcP1 + koff_, &lds_b[b_][dst1]);             \
    }

#define K_BODY(KT, DOSTAGE)                                                  \
    {                                                                        \
        int b_ = (KT) & 3;                                                   \
        if (DOSTAGE) STAGE((KT) + 3);                                        \
        intx4 af[8], bv[4];                                                  \
        _Pragma("unroll") for (int mt = 0; mt < 8; ++mt)                     \
            af[mt] = *(const intx4*)&lds_a[b_][offA[mt]];                    \
        _Pragma("unroll") for (int nt = 0; nt < 4; ++nt)                     \
            bv[nt] = *(const intx4*)&lds_b[b_][offB[nt]];                    \
        __builtin_amdgcn_s_setprio(1);                                       \
        _Pragma("unroll") for (int mt = 0; mt < 8; ++mt)                     \
            _Pragma("unroll") for (int nt = 0; nt < 4; ++nt)                 \
                acc[mt][nt] = __builtin_amdgcn_mfma_i32_16x16x64_i8(         \
                    af[mt], bv[nt], acc[mt][nt], 0, 0, 0);                   \
        __builtin_amdgcn_s_setprio(0);                                       \
    }

    // Prologue: 3 K-tiles in flight (12 load-instrs/thread).
    STAGE(0);
    STAGE(1);
    STAGE(2);

    // 16 K-steps. At top of step kt, loads newer than kt's are kt+1's and
    // kt+2's (8 instrs) -> vmcnt(8) forces kt's 4 complete; barrier
    // publishes them. Stage targets buf (kt+3)&3 == (kt-1)&3, whose reads
    // drained before this step's top barrier.
    for (int kt = 0; kt < 13; ++kt) {
        asm volatile("s_waitcnt vmcnt(8)" ::: "memory");
        __builtin_amdgcn_s_barrier();
        asm volatile("" ::: "memory");
        K_BODY(kt, 1);
    }
    asm volatile("s_waitcnt vmcnt(8)" ::: "memory");
    __builtin_amdgcn_s_barrier();
    asm volatile("" ::: "memory");
    K_BODY(13, 0);
    asm volatile("s_waitcnt vmcnt(4)" ::: "memory");
    __builtin_amdgcn_s_barrier();
    asm volatile("" ::: "memory");
    K_BODY(14, 0);
    asm volatile("s_waitcnt vmcnt(0)" ::: "memory");
    __builtin_amdgcn_s_barrier();
    asm volatile("" ::: "memory");
    K_BODY(15, 0);

#undef K_BODY
#undef STAGE

    // Epilogue. C/D layout: col = l16, row = quad*4 + r (dtype-independent).
    // score = 20/(448*448) * int-dot.
    const float SC = SCALEF / (SQ * SQ);
    bool diag_block = (tile_m == tile_n);
    float psum[8][4];
#pragma unroll
    for (int mt = 0; mt < 8; ++mt)
#pragma unroll
        for (int r = 0; r < 4; ++r) psum[mt][r] = 0.0f;

#pragma unroll
    for (int mt = 0; mt < 8; ++mt)
#pragma unroll
        for (int nt = 0; nt < 4; ++nt)
#pragma unroll
            for (int r = 0; r < 4; ++r) {
                float sc = SC * (float)acc[mt][nt][r];
                psum[mt][r] += __expf(sc - SCALEF);  // scores in ~[-20,20]
                if (diag_block) {
                    int rt = wm * 128 + mt * 16 + quad * 4 + r;
                    int ct = wn * 64 + nt * 16 + l16;
                    if (rt == ct)
                        __hip_atomic_store(&diag[tile_m * 256 + rt], sc,
                                           __ATOMIC_RELAXED,
                                           __HIP_MEMORY_SCOPE_AGENT);
                }
            }

    // Cross-l16 reduce, then cross-wn reduce in LDS -> 1 atomic per row.
    // lds_a[0] last read at kt=12; every wave has passed >=3 barriers since.
    float* part = (float*)&lds_a[0][0];  // [4 wn][256 rows]
#pragma unroll
    for (int mt = 0; mt < 8; ++mt)
#pragma unroll
        for (int r = 0; r < 4; ++r) {
            float v = psum[mt][r];
            v += __shfl_xor(v, 1, 64);
            v += __shfl_xor(v, 2, 64);
            v += __shfl_xor(v, 4, 64);
            v += __shfl_xor(v, 8, 64);
            if (l16 == 0) part[wn * 256 + wm * 128 + mt * 16 + quad * 4 + r] = v;
        }
    __syncthreads();
    if (t < 256) {
        float s = part[t] + part[256 + t] + part[512 + t] + part[768 + t];
        atomicAdd(&rowsum[tile_m * 256 + t], s);  // device-scope, coherent
    }

    // ---- fused finalize, all-RELAXED (no fences -> no L2 wb/inv).
    // __syncthreads' pre-barrier vmcnt(0) drains every wave's rowsum/diag
    // atomics before t0 increments the panel counter; atomics are coherent
    // at device scope, so the 16th increment implies all panel data landed.
    __syncthreads();
    if (t == 0) {
        int old = __hip_atomic_fetch_add(&cnt[tile_m], 1, __ATOMIC_RELAXED,
                                         __HIP_MEMORY_SCOPE_AGENT);
        is_last = (old == 15);
    }
    __syncthreads();
    if (is_last) {
        if (t < 256) {
            int i = tile_m * 256 + t;
            float rs = __hip_atomic_load(&rowsum[i], __ATOMIC_RELAXED,
                                         __HIP_MEMORY_SCOPE_AGENT);
            float dg = __hip_atomic_load(&diag[i], __ATOMIC_RELAXED,
                                         __HIP_MEMORY_SCOPE_AGENT);
            float local = (logf(rs) + SCALEF) - dg;
            local += __shfl_xor(local, 1, 64);
            local += __shfl_xor(local, 2, 64);
            local += __shfl_xor(local, 4, 64);
            local += __shfl_xor(local, 8, 64);
            local += __shfl_xor(local, 16, 64);
            local += __shfl_xor(local, 32, 64);
            if ((t & 63) == 0) atomicAdd(out, local * (1.0f / (float)NB));
        }
    }
}

// ---------------------------------------------------------------------------
extern "C" void kernel_launch(void* const* d_in, const int* in_sizes, int n_in,
                              void* d_out, int out_size, void* d_ws, size_t ws_size,
                              hipStream_t stream) {
    const float* A = (const float*)d_in[0];
    const float* P = (const float*)d_in[1];

    signed char* Aq = (signed char*)d_ws;                 // 4 MiB
    signed char* Pq = Aq + (size_t)NB * ND;               // 4 MiB
    float* rowsum = (float*)(Pq + (size_t)NB * ND);       // 16 KiB (zeroed in cvt)
    float* diag = rowsum + NB;                            // 16 KiB
    int* cnt = (int*)(diag + NB);                         // 64 B (zeroed in cvt)

    mnrl_norm_cvt<<<2 * NB / 4, 256, 0, stream>>>(A, P, Aq, Pq, rowsum, cnt,
                                                  (float*)d_out);
    mnrl_gemm_lse<<<16 * 16, 512, 0, stream>>>(Aq, Pq, rowsum, diag, cnt,
                                               (float*)d_out);
}

// Round 14
// 98.395 us; speedup vs baseline: 1.0351x; 1.0351x over previous
//
#include <hip/hip_runtime.h>
#include <math.h>

#define NB 4096
#define ND 1024
#define SCALEF 20.0f
#define SQ 448.0f  // int8 quant scale for unit-norm rows (|x|max ~0.15 -> |q| <= ~67)

typedef int intx4 __attribute__((ext_vector_type(4)));

__device__ __forceinline__ void load16_to_lds(const void* g, void* l) {
    __builtin_amdgcn_global_load_lds(
        (const __attribute__((address_space(1))) void*)g,
        (__attribute__((address_space(3))) void*)l, 16, 0, 0);
}

__device__ __forceinline__ int q8(float x) {
    float c = fminf(fmaxf(x, -127.0f), 127.0f);
    return (int)rintf(c);
}

// ---------------------------------------------------------------------------
// Kernel 1: fused L2-normalize + fp32 -> int8 quantize (q = rint(448 * x^)),
// one wave per row. Packs 4 i8 per dword in k-order. Zeroes rowsum and out.
// ---------------------------------------------------------------------------
__global__ __launch_bounds__(256) void mnrl_norm_cvt(
    const float* __restrict__ A, const float* __restrict__ P,
    signed char* __restrict__ Aq, signed char* __restrict__ Pq,
    float* __restrict__ rowsum, float* __restrict__ out) {
    if (blockIdx.x == 0 && threadIdx.x == 0) out[0] = 0.0f;
    int row = blockIdx.x * 4 + (threadIdx.x >> 6);  // 0..8191
    int lane = threadIdx.x & 63;
    bool is_a = row < NB;
    const float* src = is_a ? (A + (size_t)row * ND)
                            : (P + (size_t)(row - NB) * ND);
    unsigned int* dst = (unsigned int*)(is_a ? (Aq + (size_t)row * ND)
                                             : (Pq + (size_t)(row - NB) * ND));

    float4 v[4];
    float ss = 0.0f;
#pragma unroll
    for (int i = 0; i < 4; ++i) {
        v[i] = ((const float4*)src)[i * 64 + lane];
        ss += v[i].x * v[i].x + v[i].y * v[i].y + v[i].z * v[i].z + v[i].w * v[i].w;
    }
#pragma unroll
    for (int off = 32; off > 0; off >>= 1) ss += __shfl_xor(ss, off, 64);
    float inv = SQ / fmaxf(sqrtf(ss), 1e-8f);
#pragma unroll
    for (int i = 0; i < 4; ++i) {
        int q0 = q8(v[i].x * inv), q1 = q8(v[i].y * inv);
        int q2 = q8(v[i].z * inv), q3 = q8(v[i].w * inv);
        dst[i * 64 + lane] = (unsigned int)((q0 & 255) | ((q1 & 255) << 8) |
                                            ((q2 & 255) << 16) | (q3 << 24));
    }
    if (is_a && lane == 0) rowsum[row] = 0.0f;
}

// ---------------------------------------------------------------------------
// Kernel 2: 256x128-tile int8 MFMA GEMM (mfma_i32_16x16x64_i8), 8 waves
// (4Mx2N, wave tile 64x64 -> 64 AGPR acc), LDS 48 KiB (BK=64 ring-2),
// __launch_bounds__(512,4) -> 2 blocks/CU. Best-measured configuration
// (round 12, 99.7 us total). No device-scope fences (round-9 lesson:
// agent fence = per-block L2 writeback, +30 us). Fused exp-sum + diag.
//
// LDS geometry (verified 0 conflicts): row = 64 B = 4 chunks of 16 B;
// chunk c of row r at slot c^((r>>1)&3); fetch side pre-swizzles the
// per-lane global address (gload_lds dest is linear); read side slot =
// quad^((l16>>1)&3).
// ---------------------------------------------------------------------------
__global__ __launch_bounds__(512, 4) void mnrl_gemm_lse(
    const signed char* __restrict__ Aq, const signed char* __restrict__ Pq,
    float* __restrict__ rowsum, float* __restrict__ diag) {
    __shared__ __align__(16) unsigned char lds_a[2][256 * 64];  // 16 KiB/buf
    __shared__ __align__(16) unsigned char lds_b[2][128 * 64];  // 8 KiB/buf

    // XCD-aware swizzle: 512 blocks, 8 XCDs -> 64 contiguous tiles per XCD.
    int bid = blockIdx.x;
    int swz = (bid & 7) * 64 + (bid >> 3);
    int tile_m = swz >> 5;  // 0..15 (256-row A panel)
    int tile_n = swz & 31;  // 0..31 (128-row B panel)

    int t = threadIdx.x;
    int lane = t & 63;
    int w = t >> 6;   // 0..7
    int wm = w >> 1;  // 0..3  (64-row quarter)
    int wn = w & 1;   // 0..1  (64-col half)
    int quad = lane >> 4;
    int l16 = lane & 15;

    const signed char* Abase = Aq + (size_t)tile_m * 256 * ND;
    const signed char* Pbase = Pq + (size_t)tile_n * 128 * ND;

    // Staging: per 1 KiB issue (16 rows), lane l -> row l>>2, LDS slot l&3,
    // fetch global chunk (l&3)^((l>>3)&3) so slot s of row r holds chunk
    // s^((r>>1)&3). Wave w: A rows w*32..+32 (2 issues), B rows w*16..+16
    // (1 issue) -> 3 gload_lds per thread per K-step.
    int srow = lane >> 2;
    int chunk = (lane & 3) ^ ((lane >> 3) & 3);
    const signed char* srcA0 = Abase + (size_t)(w * 32 + srow) * ND + chunk * 16;
    const signed char* srcA1 = srcA0 + (size_t)16 * ND;
    const signed char* srcP0 = Pbase + (size_t)(w * 16 + srow) * ND + chunk * 16;
    const int dstA0 = w * 2048;
    const int dstA1 = w * 2048 + 1024;
    const int dstP = w * 1024;

    // Fragment read byte offsets. Row r: base r*64; slot = quad^((l16>>1)&3).
    int slot16 = (quad ^ ((l16 >> 1) & 3)) * 16;
    int offA[4], offB[4];
#pragma unroll
    for (int mt = 0; mt < 4; ++mt)
        offA[mt] = (wm * 64 + mt * 16 + l16) * 64 + slot16;
#pragma unroll
    for (int nt = 0; nt < 4; ++nt)
        offB[nt] = (wn * 64 + nt * 16 + l16) * 64 + slot16;

    intx4 acc[4][4];  // 64 i32 accumulator regs/lane (AGPR)
#pragma unroll
    for (int mt = 0; mt < 4; ++mt)
#pragma unroll
        for (int nt = 0; nt < 4; ++nt) acc[mt][nt] = (intx4){0, 0, 0, 0};

#define STAGE(KT)                                                   \
    {                                                               \
        int koff_ = (KT) * 64;                                      \
        int b_ = (KT) & 1;                                          \
        load16_to_lds(srcA0 + koff_, &lds_a[b_][dstA0]);            \
        load16_to_lds(srcA1 + koff_, &lds_a[b_][dstA1]);            \
        load16_to_lds(srcP0 + koff_, &lds_b[b_][dstP]);             \
    }

    STAGE(0);

    // 16 K-steps, ring-2: wait this step's loads (only ones outstanding),
    // publish via barrier, issue next step's into the other buffer (its
    // readers drained before the barrier we crossed). The drain stall is
    // covered by the co-resident block on the same CU.
    for (int kt = 0; kt < 16; ++kt) {
        asm volatile("s_waitcnt vmcnt(0)" ::: "memory");
        __builtin_amdgcn_s_barrier();
        asm volatile("" ::: "memory");
        if (kt < 15) STAGE(kt + 1);
        const unsigned char* ba = &lds_a[kt & 1][0];
        const unsigned char* bb = &lds_b[kt & 1][0];
        intx4 af[4], bv[4];
#pragma unroll
        for (int mt = 0; mt < 4; ++mt) af[mt] = *(const intx4*)&ba[offA[mt]];
#pragma unroll
        for (int nt = 0; nt < 4; ++nt) bv[nt] = *(const intx4*)&bb[offB[nt]];
        __builtin_amdgcn_s_setprio(1);
#pragma unroll
        for (int mt = 0; mt < 4; ++mt)
#pragma unroll
            for (int nt = 0; nt < 4; ++nt)
                acc[mt][nt] = __builtin_amdgcn_mfma_i32_16x16x64_i8(
                    af[mt], bv[nt], acc[mt][nt], 0, 0, 0);
        __builtin_amdgcn_s_setprio(0);
    }
#undef STAGE

    // Epilogue. C/D layout: col = l16, row = quad*4 + r (dtype-independent).
    // score = 20/(448*448) * int-dot.
    const float SC = SCALEF / (SQ * SQ);
    // Diagonal lives here iff tile_n>>1 == tile_m; local col = local row -
    // (tile_n odd ? 128 : 0).
    bool diag_block = ((tile_n >> 1) == tile_m);
    int coff = (tile_n & 1) * 128;
    float psum[4][4];
#pragma unroll
    for (int mt = 0; mt < 4; ++mt)
#pragma unroll
        for (int r = 0; r < 4; ++r) psum[mt][r] = 0.0f;

#pragma unroll
    for (int mt = 0; mt < 4; ++mt)
#pragma unroll
        for (int nt = 0; nt < 4; ++nt)
#pragma unroll
            for (int r = 0; r < 4; ++r) {
                float sc = SC * (float)acc[mt][nt][r];
                psum[mt][r] += __expf(sc - SCALEF);  // scores in ~[-20,20]
                if (diag_block) {
                    int rt = wm * 64 + mt * 16 + quad * 4 + r;  // 0..255
                    int ct = wn * 64 + nt * 16 + l16;           // 0..127
                    if (rt == ct + coff) diag[tile_m * 256 + rt] = sc;
                }
            }

    // Cross-l16 reduce, then cross-wn reduce in LDS -> 1 atomic per row.
    // part[] (2 KiB) reuses lds_a[0]: after kt=15's top barrier no wave
    // reads buffer 0 again, so post-loop writes are race-free.
    float* part = (float*)&lds_a[0][0];  // [2 wn][256 rows]
#pragma unroll
    for (int mt = 0; mt < 4; ++mt)
#pragma unroll
        for (int r = 0; r < 4; ++r) {
            float v = psum[mt][r];
            v += __shfl_xor(v, 1, 64);
            v += __shfl_xor(v, 2, 64);
            v += __shfl_xor(v, 4, 64);
            v += __shfl_xor(v, 8, 64);
            if (l16 == 0) part[wn * 256 + wm * 64 + mt * 16 + quad * 4 + r] = v;
        }
    __syncthreads();
    if (t < 256) {
        float s = part[t] + part[256 + t];
        atomicAdd(&rowsum[tile_m * 256 + t], s);
    }
}

// ---------------------------------------------------------------------------
// Kernel 3: loss = mean(log(rowsum) + 20 - diag). 16 blocks, atomic merge.
// ---------------------------------------------------------------------------
__global__ __launch_bounds__(256) void mnrl_finalize(const float* __restrict__ rowsum,
                                                     const float* __restrict__ diag,
                                                     float* __restrict__ out) {
    int t = threadIdx.x;
    int i = blockIdx.x * 256 + t;  // 16*256 = 4096
    float local = (logf(rowsum[i]) + SCALEF) - diag[i];
#pragma unroll
    for (int off = 32; off > 0; off >>= 1) local += __shfl_down(local, off, 64);
    __shared__ float sred[4];
    if ((t & 63) == 0) sred[t >> 6] = local;
    __syncthreads();
    if (t == 0)
        atomicAdd(out, (sred[0] + sred[1] + sred[2] + sred[3]) * (1.0f / (float)NB));
}

// ---------------------------------------------------------------------------
extern "C" void kernel_launch(void* const* d_in, const int* in_sizes, int n_in,
                              void* d_out, int out_size, void* d_ws, size_t ws_size,
                              hipStream_t stream) {
    const float* A = (const float*)d_in[0];
    const float* P = (const float*)d_in[1];

    signed char* Aq = (signed char*)d_ws;                 // 4 MiB
    signed char* Pq = Aq + (size_t)NB * ND;               // 4 MiB
    float* rowsum = (float*)(Pq + (size_t)NB * ND);       // 16 KiB (zeroed in cvt)
    float* diag = rowsum + NB;                            // 16 KiB

    mnrl_norm_cvt<<<2 * NB / 4, 256, 0, stream>>>(A, P, Aq, Pq, rowsum,
                                                  (float*)d_out);
    mnrl_gemm_lse<<<16 * 32, 512, 0, stream>>>(Aq, Pq, rowsum, diag);
    mnrl_finalize<<<16, 256, 0, stream>>>(rowsum, diag, (float*)d_out);
}